// Round 5
// baseline (3686.042 us; speedup 1.0000x reference)
//
#include <hip/hip_runtime.h>

constexpr int NN = 100000;   // nodes
constexpr int NE = 1600000;  // edges
constexpr int NG = 5000;     // graphs
constexpr int BKT = 64;      // dst-nodes per bucket
constexpr int NBKT = (NN + BKT - 1) / BKT;   // 1563
constexpr int NB = 128;      // hist/scatter blocks
constexpr int CHUNK = NE / NB;               // 12500 exact

typedef float v2f __attribute__((ext_vector_type(2)));

// ---- workspace layout (4B words) ----
constexpr size_t OFF_G  = 2000000;                      // g      [NG*10]
constexpr size_t OFF_BH = OFF_G + 50000;                // bh     [NB][NBKT]
constexpr size_t OFF_ST = OFF_BH + (size_t)NB * NBKT;   // starts [NBKT+1]
constexpr size_t OFF_PM = OFF_ST + NBKT + 1;            // perm   [NE]

// ---------------- pass A: per-block bucket histogram (+ zero g) ----------------
__global__ __launch_bounds__(256) void k_hist(const int* __restrict__ ei,
                                              int* __restrict__ bh,
                                              float* __restrict__ g) {
  __shared__ int lh[NBKT];
  for (int i = threadIdx.x; i < NBKT; i += 256) lh[i] = 0;
  __syncthreads();
  const int* dstp = ei + NE;
  int s = blockIdx.x * CHUNK;
  for (int i = s + threadIdx.x; i < s + CHUNK; i += 256)
    atomicAdd(&lh[dstp[i] >> 6], 1);                    // LDS int atomic
  int gid = blockIdx.x * 256 + threadIdx.x;             // zero g: 12,500 float4
  if (gid < 12500) ((float4*)g)[gid] = make_float4(0.f, 0.f, 0.f, 0.f);
  __syncthreads();
  int* out = bh + (size_t)blockIdx.x * NBKT;            // block-major: coalesced
  for (int k = threadIdx.x; k < NBKT; k += 256) out[k] = lh[k];
}

// ---------------- pass B: scan (single block, 1024 thr, 2 buckets/thread) ----------------
__global__ __launch_bounds__(1024) void k_scan(int* __restrict__ bh, int* __restrict__ starts) {
  __shared__ int s0[1024], s1[1024];
  int t = threadIdx.x;
  int k0 = 2 * t, k1 = 2 * t + 1;
  int tot0 = 0, tot1 = 0;
  for (int b = 0; b < NB; ++b) {                        // coalesced (t-consecutive)
    const int* row = bh + (size_t)b * NBKT;
    if (k0 < NBKT) tot0 += row[k0];
    if (k1 < NBKT) tot1 += row[k1];
  }
  int ssum = tot0 + tot1;
  int* cur = s0; int* nxt = s1;
  cur[t] = ssum;
  __syncthreads();
  for (int off = 1; off < 1024; off <<= 1) {            // Hillis-Steele inclusive
    int v = cur[t];
    if (t >= off) v += cur[t - off];
    nxt[t] = v;
    __syncthreads();
    int* tmp = cur; cur = nxt; nxt = tmp;
  }
  int excl = cur[t] - ssum;
  if (k0 < NBKT) starts[k0] = excl;
  if (k1 <= NBKT) starts[k1] = excl + tot0;             // k1==NBKT writes starts[NBKT]=NE
  int run0 = excl, run1 = excl + tot0;
  for (int b = 0; b < NB; ++b) {                        // per-(block,bucket) bases
    int* row = bh + (size_t)b * NBKT;
    if (k0 < NBKT) { int v = row[k0]; row[k0] = run0; run0 += v; }
    if (k1 < NBKT) { int v = row[k1]; row[k1] = run1; run1 += v; }
  }
}

// ---------------- pass C: scatter edge ids into bucket order ----------------
__global__ __launch_bounds__(256) void k_scatter(const int* __restrict__ ei,
                                                 const int* __restrict__ bh,
                                                 int* __restrict__ perm) {
  __shared__ int base[NBKT];
  __shared__ int cnt[NBKT];
  const int* row = bh + (size_t)blockIdx.x * NBKT;
  for (int k = threadIdx.x; k < NBKT; k += 256) { base[k] = row[k]; cnt[k] = 0; }
  __syncthreads();
  const int* dstp = ei + NE;
  int s = blockIdx.x * CHUNK;
  for (int i = s + threadIdx.x; i < s + CHUNK; i += 256) {
    int d = dstp[i];
    int k = d >> 6;
    int r = atomicAdd(&cnt[k], 1);                      // LDS atomic
    perm[base[k] + r] = i | ((d & 63) << 24);           // edge id (21b) | dst-low6 <<24
  }
}

#define ST4(A, B, V) { A[B] = (V).x; A[B+1] = (V).y; A[B+2] = (V).z; A[B+3] = (V).w; }

// ---------------- pass D: edge MLP + LDS-tile scatter ----------------
// Weights in LDS (wave-uniform ds_read_b128 broadcast); packed v_pk_fma_f32 math.
__global__ __launch_bounds__(256, 4) void k_edge(
    const int* __restrict__ ei,
    const float* __restrict__ nattr,
    const float* __restrict__ eattr,
    const float* __restrict__ Wm,
    const float* __restrict__ bm,
    const int* __restrict__ perm,
    const int* __restrict__ starts,
    float* __restrict__ x) {
  __shared__ float Wl[960];        // 48 x 20
  __shared__ float bl[20];
  __shared__ float xt[BKT * 20];   // feature-major tile xt[j*64+dl]
  __shared__ int s_se[2];
  for (int i = threadIdx.x; i < 960; i += 256) Wl[i] = Wm[i];
  if (threadIdx.x < 20) bl[threadIdx.x] = bm[threadIdx.x];
  for (int i = threadIdx.x; i < BKT * 20; i += 256) xt[i] = 0.f;
  if (threadIdx.x < 2) s_se[threadIdx.x] = starts[blockIdx.x + threadIdx.x];
  __syncthreads();
  int is = s_se[0], ie = s_se[1];
  int nbase = blockIdx.x * BKT;

  int i  = is + (int)threadIdx.x;
  int pC = (i < ie) ? perm[i] : 0;
  int sC = (i < ie) ? ei[pC & 0xFFFFFF] : 0;
  while (i < ie) {
    int inx = i + 256;                                  // prefetch next iter's chain
    int pN = (inx < ie) ? perm[inx] : 0;
    int sN = (inx < ie) ? ei[pN & 0xFFFFFF] : 0;

    int e  = pC & 0xFFFFFF;
    int dl = (pC >> 24) & 63;
    const float4* ps = (const float4*)(nattr + (size_t)sC * 16);
    const float4* pd = (const float4*)(nattr + (size_t)(nbase + dl) * 16);
    const float4* pe = (const float4*)(eattr + (size_t)e * 16);

    float f[48];                                        // constant-index only -> SROA
    { float4 t0 = ps[0], t1 = ps[1], t2 = ps[2], t3 = ps[3];
      ST4(f, 0, t0) ST4(f, 4, t1) ST4(f, 8, t2) ST4(f, 12, t3) }
    { float4 t0 = pd[0], t1 = pd[1], t2 = pd[2], t3 = pd[3];
      ST4(f, 16, t0) ST4(f, 20, t1) ST4(f, 24, t2) ST4(f, 28, t3) }
    { float4 t0 = pe[0], t1 = pe[1], t2 = pe[2], t3 = pe[3];
      ST4(f, 32, t0) ST4(f, 36, t1) ST4(f, 40, t2) ST4(f, 44, t3) }

    v2f acc[10];
    { float4 b0 = *(const float4*)&bl[0], b1 = *(const float4*)&bl[4],
             b2 = *(const float4*)&bl[8], b3 = *(const float4*)&bl[12],
             b4 = *(const float4*)&bl[16];
      acc[0] = v2f{b0.x, b0.y}; acc[1] = v2f{b0.z, b0.w};
      acc[2] = v2f{b1.x, b1.y}; acc[3] = v2f{b1.z, b1.w};
      acc[4] = v2f{b2.x, b2.y}; acc[5] = v2f{b2.z, b2.w};
      acc[6] = v2f{b3.x, b3.y}; acc[7] = v2f{b3.z, b3.w};
      acc[8] = v2f{b4.x, b4.y}; acc[9] = v2f{b4.z, b4.w}; }
#pragma unroll
    for (int k = 0; k < 48; ++k) {
      float fk = f[k];
      v2f fk2 = {fk, fk};
#pragma unroll
      for (int jq = 0; jq < 5; ++jq) {
        float4 w = *(const float4*)&Wl[k * 20 + jq * 4];  // wave-uniform -> broadcast
        acc[jq*2]   = __builtin_elementwise_fma(fk2, v2f{w.x, w.y}, acc[jq*2]);
        acc[jq*2+1] = __builtin_elementwise_fma(fk2, v2f{w.z, w.w}, acc[jq*2+1]);
      }
    }
#pragma unroll
    for (int j = 0; j < 20; ++j) {
      float m = fmaxf(acc[j >> 1][j & 1], 0.f);
      if (m > 0.f) atomicAdd(&xt[j * BKT + dl], m);     // LDS fp atomic
    }
    pC = pN; sC = sN; i = inx;
  }
  __syncthreads();

  int nn = min(BKT, NN - nbase);
  float* xo = x + (size_t)nbase * 20;
  for (int idx = threadIdx.x; idx < nn * 20; idx += 256) {  // coalesced stores
    int node = idx / 20;
    int j = idx - node * 20;
    xo[idx] = xt[j * BKT + node];
  }
}

// ---------------- node MLP + pool to graphs (sorted batch -> LDS partials) ----------------
constexpr int SPAN = 512;
__global__ __launch_bounds__(256) void k_node(
    const float* __restrict__ x,
    const int* __restrict__ batch,
    const float* __restrict__ W1,
    const float* __restrict__ b1,
    float* __restrict__ g) {
  __shared__ float gacc[SPAN * 10];
  __shared__ int s_bmin;
  for (int i = threadIdx.x; i < SPAN * 10; i += 256) gacc[i] = 0.f;
  int n0 = blockIdx.x * 256;
  if (threadIdx.x == 0) s_bmin = batch[n0];
  __syncthreads();
  int bmin = s_bmin;
  int n = n0 + threadIdx.x;
  if (n < NN) {
    float xi[20];
    const float4* px = (const float4*)(x + (size_t)n * 20);
    { float4 t0 = px[0], t1 = px[1], t2 = px[2], t3 = px[3], t4 = px[4];
      ST4(xi, 0, t0) ST4(xi, 4, t1) ST4(xi, 8, t2) ST4(xi, 12, t3) ST4(xi, 16, t4) }
    float acc[10];
#pragma unroll
    for (int j = 0; j < 10; ++j) acc[j] = b1[j];
#pragma unroll
    for (int k = 0; k < 20; ++k) {
      float fk = xi[k];
#pragma unroll
      for (int j = 0; j < 10; ++j) acc[j] = fmaf(fk, W1[k * 10 + j], acc[j]);
    }
    int bn = batch[n];
    int d = bn - bmin;
    if (d < SPAN) {
#pragma unroll
      for (int j = 0; j < 10; ++j) {
        float m = fmaxf(acc[j], 0.f);
        if (m > 0.f) atomicAdd(&gacc[d * 10 + j], m);   // LDS
      }
    } else {
#pragma unroll
      for (int j = 0; j < 10; ++j) {
        float m = fmaxf(acc[j], 0.f);
        if (m > 0.f) unsafeAtomicAdd(&g[(size_t)bn * 10 + j], m);
      }
    }
  }
  __syncthreads();
  int lim = min(SPAN * 10, NG * 10 - bmin * 10);
  float* gp = g + (size_t)bmin * 10;
  for (int idx = threadIdx.x; idx < lim; idx += 256) {
    float v = gacc[idx];
    if (v != 0.f) unsafeAtomicAdd(&gp[idx], v);         // sparse residuals
  }
}

// ---------------- graph MLP ----------------
__global__ __launch_bounds__(256) void k_graph(
    const float* __restrict__ g,
    const float* __restrict__ W2, const float* __restrict__ b2,
    const float* __restrict__ W3, const float* __restrict__ b3,
    float* __restrict__ out) {
  int i = blockIdx.x * 256 + threadIdx.x;
  if (i >= NG) return;
  float gi[10];
  const float2* pg = (const float2*)(g + (size_t)i * 10);
#pragma unroll
  for (int k = 0; k < 5; ++k) { float2 v = pg[k]; gi[2*k] = v.x; gi[2*k+1] = v.y; }
  float o = b3[0];
#pragma unroll
  for (int j = 0; j < 10; ++j) {
    float a = b2[j];
#pragma unroll
    for (int k = 0; k < 10; ++k) a = fmaf(gi[k], W2[k * 10 + j], a);
    o = fmaf(fmaxf(a, 0.f), W3[j], o);
  }
  out[i] = o;
}

extern "C" void kernel_launch(void* const* d_in, const int* in_sizes, int n_in,
                              void* d_out, int out_size, void* d_ws, size_t ws_size,
                              hipStream_t stream) {
  const int*   ei    = (const int*)  d_in[0];
  const float* nattr = (const float*)d_in[1];
  const float* eattr = (const float*)d_in[2];
  const int*   batch = (const int*)  d_in[3];
  const float* Wm    = (const float*)d_in[4];
  const float* bm    = (const float*)d_in[5];
  const float* W1    = (const float*)d_in[6];
  const float* b1    = (const float*)d_in[7];
  const float* W2    = (const float*)d_in[8];
  const float* b2    = (const float*)d_in[9];
  const float* W3    = (const float*)d_in[10];
  const float* b3    = (const float*)d_in[11];

  float* x      = (float*)d_ws;
  float* g      = (float*)d_ws + OFF_G;
  int*   bh     = (int*)d_ws + OFF_BH;
  int*   starts = (int*)d_ws + OFF_ST;
  int*   perm   = (int*)d_ws + OFF_PM;

  k_hist   <<<NB, 256, 0, stream>>>(ei, bh, g);
  k_scan   <<<1, 1024, 0, stream>>>(bh, starts);
  k_scatter<<<NB, 256, 0, stream>>>(ei, bh, perm);
  k_edge   <<<NBKT, 256, 0, stream>>>(ei, nattr, eattr, Wm, bm, perm, starts, x);
  k_node   <<<(NN + 255) / 256, 256, 0, stream>>>(x, batch, W1, b1, g);
  k_graph  <<<(NG + 255) / 256, 256, 0, stream>>>(g, W2, b2, W3, b3, (float*)d_out);
}

// Round 6
// 578.982 us; speedup vs baseline: 6.3664x; 6.3664x over previous
//
#include <hip/hip_runtime.h>

constexpr int NN = 100000;   // nodes
constexpr int NE = 1600000;  // edges
constexpr int NG = 5000;     // graphs
constexpr int BKT = 64;      // dst-nodes per bucket
constexpr int NBKT = (NN + BKT - 1) / BKT;   // 1563
constexpr int NB = 128;      // hist/scatter blocks
constexpr int CHUNK = NE / NB;               // 12500 exact

typedef float v2f __attribute__((ext_vector_type(2)));

// ---- workspace layout (4B words) ----
constexpr size_t OFF_G  = 2000000;                      // g      [NG*10]
constexpr size_t OFF_BH = OFF_G + 50000;                // bh     [NB][NBKT]
constexpr size_t OFF_ST = OFF_BH + (size_t)NB * NBKT;   // starts [NBKT+1]
constexpr size_t OFF_PM = OFF_ST + NBKT + 1;            // perm   [NE]

// ---------------- pass A: per-block bucket histogram (+ zero g) ----------------
__global__ __launch_bounds__(256) void k_hist(const int* __restrict__ ei,
                                              int* __restrict__ bh,
                                              float* __restrict__ g) {
  __shared__ int lh[NBKT];
  for (int i = threadIdx.x; i < NBKT; i += 256) lh[i] = 0;
  __syncthreads();
  const int* dstp = ei + NE;
  int s = blockIdx.x * CHUNK;
  for (int i = s + threadIdx.x; i < s + CHUNK; i += 256)
    atomicAdd(&lh[dstp[i] >> 6], 1);                    // LDS int atomic
  int gid = blockIdx.x * 256 + threadIdx.x;             // zero g: 12,500 float4
  if (gid < 12500) ((float4*)g)[gid] = make_float4(0.f, 0.f, 0.f, 0.f);
  __syncthreads();
  int* out = bh + (size_t)blockIdx.x * NBKT;            // block-major: coalesced
  for (int k = threadIdx.x; k < NBKT; k += 256) out[k] = lh[k];
}

// ---------------- pass B: scan (single block, 1024 thr, 2 buckets/thread) ----------------
__global__ __launch_bounds__(1024) void k_scan(int* __restrict__ bh, int* __restrict__ starts) {
  __shared__ int s0[1024], s1[1024];
  int t = threadIdx.x;
  int k0 = 2 * t, k1 = 2 * t + 1;
  int tot0 = 0, tot1 = 0;
  for (int b = 0; b < NB; ++b) {                        // coalesced (t-consecutive)
    const int* row = bh + (size_t)b * NBKT;
    if (k0 < NBKT) tot0 += row[k0];
    if (k1 < NBKT) tot1 += row[k1];
  }
  int ssum = tot0 + tot1;
  int* cur = s0; int* nxt = s1;
  cur[t] = ssum;
  __syncthreads();
  for (int off = 1; off < 1024; off <<= 1) {            // Hillis-Steele inclusive
    int v = cur[t];
    if (t >= off) v += cur[t - off];
    nxt[t] = v;
    __syncthreads();
    int* tmp = cur; cur = nxt; nxt = tmp;
  }
  int excl = cur[t] - ssum;
  if (k0 < NBKT) starts[k0] = excl;
  if (k1 <= NBKT) starts[k1] = excl + tot0;             // k1==NBKT writes starts[NBKT]=NE
  int run0 = excl, run1 = excl + tot0;
  for (int b = 0; b < NB; ++b) {                        // per-(block,bucket) bases
    int* row = bh + (size_t)b * NBKT;
    if (k0 < NBKT) { int v = row[k0]; row[k0] = run0; run0 += v; }
    if (k1 < NBKT) { int v = row[k1]; row[k1] = run1; run1 += v; }
  }
}

// ---------------- pass C: scatter edge ids into bucket order ----------------
__global__ __launch_bounds__(256) void k_scatter(const int* __restrict__ ei,
                                                 const int* __restrict__ bh,
                                                 int* __restrict__ perm) {
  __shared__ int base[NBKT];
  __shared__ int cnt[NBKT];
  const int* row = bh + (size_t)blockIdx.x * NBKT;
  for (int k = threadIdx.x; k < NBKT; k += 256) { base[k] = row[k]; cnt[k] = 0; }
  __syncthreads();
  const int* dstp = ei + NE;
  int s = blockIdx.x * CHUNK;
  for (int i = s + threadIdx.x; i < s + CHUNK; i += 256) {
    int d = dstp[i];
    int k = d >> 6;
    int r = atomicAdd(&cnt[k], 1);                      // LDS atomic
    perm[base[k] + r] = i | ((d & 63) << 24);           // edge id (21b) | dst-low6 <<24
  }
}

#define ST4(A, B, V) { A[B] = (V).x; A[B+1] = (V).y; A[B+2] = (V).z; A[B+3] = (V).w; }

// ---------------- pass D: edge MLP, weights resident in VGPRs ----------------
// Lane (ep,jp): ep = edge slot (6/wave), jp = output pair (10). Each lane holds
// W[k][2jp..2jp+1] in 96 VGPRs for the whole kernel -> zero weight re-fetch.
// Feature loads: 10 lanes/edge load same addresses (TA dedups). LDS-tile scatter.
__global__ __launch_bounds__(256, 2) void k_edge(
    const int* __restrict__ ei,
    const float* __restrict__ nattr,
    const float* __restrict__ eattr,
    const float* __restrict__ Wm,
    const float* __restrict__ bm,
    const int* __restrict__ perm,
    const int* __restrict__ starts,
    float* __restrict__ x) {
  __shared__ float xt[20 * 65];    // padded rows: bank = (2jp + dl) % 32 spreads
  __shared__ int s_se[2];
  for (int i = threadIdx.x; i < 20 * 65; i += 256) xt[i] = 0.f;
  if (threadIdx.x < 2) s_se[threadIdx.x] = starts[blockIdx.x + threadIdx.x];
  __syncthreads();
  int is = s_se[0], ie = s_se[1];
  int nbase = blockIdx.x * BKT;

  int wave = threadIdx.x >> 6;
  int lane = threadIdx.x & 63;
  int ep = lane / 10;              // 0..6 (6 -> idle lane)
  int jp = lane - ep * 10;         // 0..9
  bool act = ep < 6;
  int epc = act ? ep : 0;

  v2f W[48];                       // resident weights: 96 VGPRs
#pragma unroll
  for (int k = 0; k < 48; ++k)
    W[k] = v2f{Wm[k * 20 + 2 * jp], Wm[k * 20 + 2 * jp + 1]};
  float bj0 = bm[2 * jp], bj1 = bm[2 * jp + 1];

  int base = is + wave * 6;
  int iC = base + epc;
  int pC = 0, sC = 0;
  if (base < ie) {
    pC = perm[min(iC, ie - 1)];
    sC = ei[pC & 0xFFFFFF];
  }
  while (base < ie) {
    int baseN = base + 24;                              // prefetch next chain
    int iN = baseN + epc;
    int pN = 0, sN = 0;
    if (baseN < ie) {
      pN = perm[min(iN, ie - 1)];
      sN = ei[pN & 0xFFFFFF];
    }

    int e  = pC & 0xFFFFFF;
    int dl = (pC >> 24) & 63;
    const float4* ps = (const float4*)(nattr + (size_t)sC * 16);
    const float4* pd = (const float4*)(nattr + (size_t)(nbase + dl) * 16);
    const float4* pe = (const float4*)(eattr + (size_t)e * 16);

    float f[48];                                        // constant-index only -> SROA
    { float4 t0 = ps[0], t1 = ps[1], t2 = ps[2], t3 = ps[3];
      ST4(f, 0, t0) ST4(f, 4, t1) ST4(f, 8, t2) ST4(f, 12, t3) }
    { float4 t0 = pd[0], t1 = pd[1], t2 = pd[2], t3 = pd[3];
      ST4(f, 16, t0) ST4(f, 20, t1) ST4(f, 24, t2) ST4(f, 28, t3) }
    { float4 t0 = pe[0], t1 = pe[1], t2 = pe[2], t3 = pe[3];
      ST4(f, 32, t0) ST4(f, 36, t1) ST4(f, 40, t2) ST4(f, 44, t3) }

    v2f acc = {bj0, bj1};
#pragma unroll
    for (int k = 0; k < 48; ++k) {
      v2f fk2 = {f[k], f[k]};
      acc = __builtin_elementwise_fma(fk2, W[k], acc);  // v_pk_fma_f32
    }

    bool valid = act && (iC < ie);
    float m0 = fmaxf(acc.x, 0.f);
    float m1 = fmaxf(acc.y, 0.f);
    if (valid && m0 > 0.f) atomicAdd(&xt[(2 * jp) * 65 + dl], m0);     // LDS fp atomic
    if (valid && m1 > 0.f) atomicAdd(&xt[(2 * jp + 1) * 65 + dl], m1);

    base = baseN; iC = iN; pC = pN; sC = sN;
  }
  __syncthreads();

  int nn = min(BKT, NN - nbase);
  float* xo = x + (size_t)nbase * 20;
  for (int idx = threadIdx.x; idx < nn * 20; idx += 256) {  // coalesced stores
    int node = idx / 20;
    int j = idx - node * 20;
    xo[idx] = xt[j * 65 + node];
  }
}

// ---------------- node MLP + pool to graphs (sorted batch -> LDS partials) ----------------
constexpr int SPAN = 512;
__global__ __launch_bounds__(256) void k_node(
    const float* __restrict__ x,
    const int* __restrict__ batch,
    const float* __restrict__ W1,
    const float* __restrict__ b1,
    float* __restrict__ g) {
  __shared__ float gacc[SPAN * 10];
  __shared__ int s_bmin;
  for (int i = threadIdx.x; i < SPAN * 10; i += 256) gacc[i] = 0.f;
  int n0 = blockIdx.x * 256;
  if (threadIdx.x == 0) s_bmin = batch[n0];
  __syncthreads();
  int bmin = s_bmin;
  int n = n0 + threadIdx.x;
  if (n < NN) {
    float xi[20];
    const float4* px = (const float4*)(x + (size_t)n * 20);
    { float4 t0 = px[0], t1 = px[1], t2 = px[2], t3 = px[3], t4 = px[4];
      ST4(xi, 0, t0) ST4(xi, 4, t1) ST4(xi, 8, t2) ST4(xi, 12, t3) ST4(xi, 16, t4) }
    float acc[10];
#pragma unroll
    for (int j = 0; j < 10; ++j) acc[j] = b1[j];
#pragma unroll
    for (int k = 0; k < 20; ++k) {
      float fk = xi[k];
#pragma unroll
      for (int j = 0; j < 10; ++j) acc[j] = fmaf(fk, W1[k * 10 + j], acc[j]);
    }
    int bn = batch[n];
    int d = bn - bmin;
    if (d < SPAN) {
#pragma unroll
      for (int j = 0; j < 10; ++j) {
        float m = fmaxf(acc[j], 0.f);
        if (m > 0.f) atomicAdd(&gacc[d * 10 + j], m);   // LDS
      }
    } else {
#pragma unroll
      for (int j = 0; j < 10; ++j) {
        float m = fmaxf(acc[j], 0.f);
        if (m > 0.f) unsafeAtomicAdd(&g[(size_t)bn * 10 + j], m);
      }
    }
  }
  __syncthreads();
  int lim = min(SPAN * 10, NG * 10 - bmin * 10);
  float* gp = g + (size_t)bmin * 10;
  for (int idx = threadIdx.x; idx < lim; idx += 256) {
    float v = gacc[idx];
    if (v != 0.f) unsafeAtomicAdd(&gp[idx], v);         // sparse residuals
  }
}

// ---------------- graph MLP ----------------
__global__ __launch_bounds__(256) void k_graph(
    const float* __restrict__ g,
    const float* __restrict__ W2, const float* __restrict__ b2,
    const float* __restrict__ W3, const float* __restrict__ b3,
    float* __restrict__ out) {
  int i = blockIdx.x * 256 + threadIdx.x;
  if (i >= NG) return;
  float gi[10];
  const float2* pg = (const float2*)(g + (size_t)i * 10);
#pragma unroll
  for (int k = 0; k < 5; ++k) { float2 v = pg[k]; gi[2*k] = v.x; gi[2*k+1] = v.y; }
  float o = b3[0];
#pragma unroll
  for (int j = 0; j < 10; ++j) {
    float a = b2[j];
#pragma unroll
    for (int k = 0; k < 10; ++k) a = fmaf(gi[k], W2[k * 10 + j], a);
    o = fmaf(fmaxf(a, 0.f), W3[j], o);
  }
  out[i] = o;
}

extern "C" void kernel_launch(void* const* d_in, const int* in_sizes, int n_in,
                              void* d_out, int out_size, void* d_ws, size_t ws_size,
                              hipStream_t stream) {
  const int*   ei    = (const int*)  d_in[0];
  const float* nattr = (const float*)d_in[1];
  const float* eattr = (const float*)d_in[2];
  const int*   batch = (const int*)  d_in[3];
  const float* Wm    = (const float*)d_in[4];
  const float* bm    = (const float*)d_in[5];
  const float* W1    = (const float*)d_in[6];
  const float* b1    = (const float*)d_in[7];
  const float* W2    = (const float*)d_in[8];
  const float* b2    = (const float*)d_in[9];
  const float* W3    = (const float*)d_in[10];
  const float* b3    = (const float*)d_in[11];

  float* x      = (float*)d_ws;
  float* g      = (float*)d_ws + OFF_G;
  int*   bh     = (int*)d_ws + OFF_BH;
  int*   starts = (int*)d_ws + OFF_ST;
  int*   perm   = (int*)d_ws + OFF_PM;

  k_hist   <<<NB, 256, 0, stream>>>(ei, bh, g);
  k_scan   <<<1, 1024, 0, stream>>>(bh, starts);
  k_scatter<<<NB, 256, 0, stream>>>(ei, bh, perm);
  k_edge   <<<NBKT, 256, 0, stream>>>(ei, nattr, eattr, Wm, bm, perm, starts, x);
  k_node   <<<(NN + 255) / 256, 256, 0, stream>>>(x, batch, W1, b1, g);
  k_graph  <<<(NG + 255) / 256, 256, 0, stream>>>(g, W2, b2, W3, b3, (float*)d_out);
}

// Round 7
// 442.025 us; speedup vs baseline: 8.3390x; 1.3098x over previous
//
#include <hip/hip_runtime.h>

constexpr int NN = 100000;   // nodes
constexpr int NE = 1600000;  // edges
constexpr int NG = 5000;     // graphs
constexpr int BKT = 64;      // dst-nodes per bucket
constexpr int NBKT = (NN + BKT - 1) / BKT;   // 1563
constexpr int NB = 128;      // hist/scatter blocks
constexpr int CHUNK = NE / NB;               // 12500 exact

// ---- workspace layout (4B words) ----
constexpr size_t OFF_G  = 2000000;                      // g      [NG*10]
constexpr size_t OFF_BH = OFF_G + 50000;                // bh     [NB][NBKT]
constexpr size_t OFF_ST = OFF_BH + (size_t)NB * NBKT;   // starts [NBKT+1]
constexpr size_t OFF_PM = OFF_ST + NBKT + 1;            // perm   [NE]

// ---------------- pass A: per-block bucket histogram (+ zero g) ----------------
__global__ __launch_bounds__(256) void k_hist(const int* __restrict__ ei,
                                              int* __restrict__ bh,
                                              float* __restrict__ g) {
  __shared__ int lh[NBKT];
  for (int i = threadIdx.x; i < NBKT; i += 256) lh[i] = 0;
  __syncthreads();
  const int* dstp = ei + NE;
  int s = blockIdx.x * CHUNK;
  for (int i = s + threadIdx.x; i < s + CHUNK; i += 256)
    atomicAdd(&lh[dstp[i] >> 6], 1);                    // LDS int atomic
  int gid = blockIdx.x * 256 + threadIdx.x;             // zero g: 12,500 float4
  if (gid < 12500) ((float4*)g)[gid] = make_float4(0.f, 0.f, 0.f, 0.f);
  __syncthreads();
  int* out = bh + (size_t)blockIdx.x * NBKT;            // block-major: coalesced
  for (int k = threadIdx.x; k < NBKT; k += 256) out[k] = lh[k];
}

// ---------------- pass B1: per-bucket totals (grid-parallel) ----------------
__global__ __launch_bounds__(256) void k_btot(const int* __restrict__ bh,
                                              int* __restrict__ starts) {
  int k = blockIdx.x * 256 + threadIdx.x;
  if (k >= NBKT) return;
  int tot = 0;
  for (int b = 0; b < NB; b += 4) {                     // coalesced: k-consecutive
    int a0 = bh[(size_t)(b    ) * NBKT + k];
    int a1 = bh[(size_t)(b + 1) * NBKT + k];
    int a2 = bh[(size_t)(b + 2) * NBKT + k];
    int a3 = bh[(size_t)(b + 3) * NBKT + k];
    tot += a0 + a1 + a2 + a3;
  }
  starts[k] = tot;
}

// ---------------- pass B2: exclusive scan of 1563 totals (single block, tiny) ----------------
__global__ __launch_bounds__(1024) void k_sscan(int* __restrict__ starts) {
  __shared__ int s0[1024], s1[1024];
  int t = threadIdx.x;
  int k0 = 2 * t, k1 = 2 * t + 1;
  int tot0 = (k0 < NBKT) ? starts[k0] : 0;
  int tot1 = (k1 < NBKT) ? starts[k1] : 0;
  int ssum = tot0 + tot1;
  int* cur = s0; int* nxt = s1;
  cur[t] = ssum;
  __syncthreads();
  for (int off = 1; off < 1024; off <<= 1) {            // Hillis-Steele inclusive
    int v = cur[t];
    if (t >= off) v += cur[t - off];
    nxt[t] = v;
    __syncthreads();
    int* tmp = cur; cur = nxt; nxt = tmp;
  }
  int excl = cur[t] - ssum;
  if (k0 < NBKT) starts[k0] = excl;
  if (k1 <= NBKT) starts[k1] = excl + tot0;             // t=781 writes starts[NBKT]=NE
}

// ---------------- pass B3: per-(block,bucket) bases (grid-parallel) ----------------
__global__ __launch_bounds__(256) void k_bases(int* __restrict__ bh,
                                               const int* __restrict__ starts) {
  int k = blockIdx.x * 256 + threadIdx.x;
  if (k >= NBKT) return;
  int run = starts[k];
  for (int b = 0; b < NB; ++b) {
    size_t idx = (size_t)b * NBKT + k;
    int v = bh[idx];
    bh[idx] = run;
    run += v;
  }
}

// ---------------- pass C: scatter edge ids into bucket order ----------------
__global__ __launch_bounds__(256) void k_scatter(const int* __restrict__ ei,
                                                 const int* __restrict__ bh,
                                                 int* __restrict__ perm) {
  __shared__ int base[NBKT];
  __shared__ int cnt[NBKT];
  const int* row = bh + (size_t)blockIdx.x * NBKT;
  for (int k = threadIdx.x; k < NBKT; k += 256) { base[k] = row[k]; cnt[k] = 0; }
  __syncthreads();
  const int* dstp = ei + NE;
  int s = blockIdx.x * CHUNK;
  for (int i = s + threadIdx.x; i < s + CHUNK; i += 256) {
    int d = dstp[i];
    int k = d >> 6;
    int r = atomicAdd(&cnt[k], 1);                      // LDS atomic
    perm[base[k] + r] = i | ((d & 63) << 24);           // edge id (21b) | dst-low6 <<24
  }
}

#define ST4(A, B, V) { A[B] = (V).x; A[B+1] = (V).y; A[B+2] = (V).z; A[B+3] = (V).w; }

// ---------------- pass D: edge MLP, weights pinned in VGPRs ----------------
// Lane (ep,jp): ep = edge slot (6/wave), jp = output pair (10). Lane holds
// W[k][2jp], W[k][2jp+1] in 96 VGPRs, PINNED via asm so the compiler cannot
// rematerialize the loads into the loop (R6: it demoted to per-iter L1 reloads).
__global__ __launch_bounds__(256, 2) void k_edge(
    const int* __restrict__ ei,
    const float* __restrict__ nattr,
    const float* __restrict__ eattr,
    const float* __restrict__ Wm,
    const float* __restrict__ bm,
    const int* __restrict__ perm,
    const int* __restrict__ starts,
    float* __restrict__ x) {
  __shared__ float xt[20 * 65];    // padded rows
  __shared__ int s_se[2];
  for (int i = threadIdx.x; i < 20 * 65; i += 256) xt[i] = 0.f;
  if (threadIdx.x < 2) s_se[threadIdx.x] = starts[blockIdx.x + threadIdx.x];
  __syncthreads();
  int is = s_se[0], ie = s_se[1];
  int nbase = blockIdx.x * BKT;

  int wave = threadIdx.x >> 6;
  int lane = threadIdx.x & 63;
  int ep = lane / 10;              // 0..6 (6 -> idle lane)
  int jp = lane - ep * 10;         // 0..9
  bool act = ep < 6;
  int epc = act ? ep : 0;

  float W0[48], W1[48];            // resident weights: 96 VGPRs
#pragma unroll
  for (int k = 0; k < 48; ++k) {
    W0[k] = Wm[k * 20 + 2 * jp];
    W1[k] = Wm[k * 20 + 2 * jp + 1];
  }
#pragma unroll
  for (int k = 0; k < 48; ++k) {   // pin: forbid remat/sinking into the loop
    asm volatile("" : "+v"(W0[k]));
    asm volatile("" : "+v"(W1[k]));
  }
  float bj0 = bm[2 * jp], bj1 = bm[2 * jp + 1];

  int base = is + wave * 6;
  int iC = base + epc;
  int pC = 0, sC = 0;
  if (base < ie) {
    pC = perm[min(iC, ie - 1)];
    sC = ei[pC & 0xFFFFFF];
  }
  while (base < ie) {
    int baseN = base + 24;                              // prefetch next chain
    int iN = baseN + epc;
    int pN = 0, sN = 0;
    if (baseN < ie) {
      pN = perm[min(iN, ie - 1)];
      sN = ei[pN & 0xFFFFFF];
    }

    int e  = pC & 0xFFFFFF;
    int dl = (pC >> 24) & 63;
    const float4* ps = (const float4*)(nattr + (size_t)sC * 16);
    const float4* pd = (const float4*)(nattr + (size_t)(nbase + dl) * 16);
    const float4* pe = (const float4*)(eattr + (size_t)e * 16);

    float f[48];                                        // constant-index only -> SROA
    { float4 t0 = ps[0], t1 = ps[1], t2 = ps[2], t3 = ps[3];
      ST4(f, 0, t0) ST4(f, 4, t1) ST4(f, 8, t2) ST4(f, 12, t3) }
    { float4 t0 = pd[0], t1 = pd[1], t2 = pd[2], t3 = pd[3];
      ST4(f, 16, t0) ST4(f, 20, t1) ST4(f, 24, t2) ST4(f, 28, t3) }
    { float4 t0 = pe[0], t1 = pe[1], t2 = pe[2], t3 = pe[3];
      ST4(f, 32, t0) ST4(f, 36, t1) ST4(f, 40, t2) ST4(f, 44, t3) }
#pragma unroll
    for (int k = 0; k < 48; ++k) asm volatile("" : "+v"(f[k]));  // pin features

    float a0 = bj0, a1 = bj1;
#pragma unroll
    for (int k = 0; k < 48; ++k) {
      a0 = fmaf(f[k], W0[k], a0);
      a1 = fmaf(f[k], W1[k], a1);
    }

    bool valid = act && (iC < ie);
    float m0 = fmaxf(a0, 0.f);
    float m1 = fmaxf(a1, 0.f);
    if (valid && m0 > 0.f) atomicAdd(&xt[(2 * jp) * 65 + dl], m0);     // LDS fp atomic
    if (valid && m1 > 0.f) atomicAdd(&xt[(2 * jp + 1) * 65 + dl], m1);

    base = baseN; iC = iN; pC = pN; sC = sN;
  }
  __syncthreads();

  int nn = min(BKT, NN - nbase);
  float* xo = x + (size_t)nbase * 20;
  for (int idx = threadIdx.x; idx < nn * 20; idx += 256) {  // coalesced stores
    int node = idx / 20;
    int j = idx - node * 20;
    xo[idx] = xt[j * 65 + node];
  }
}

// ---------------- node MLP + pool to graphs (sorted batch -> LDS partials) ----------------
constexpr int SPAN = 512;
__global__ __launch_bounds__(256) void k_node(
    const float* __restrict__ x,
    const int* __restrict__ batch,
    const float* __restrict__ W1,
    const float* __restrict__ b1,
    float* __restrict__ g) {
  __shared__ float gacc[SPAN * 10];
  __shared__ int s_bmin;
  for (int i = threadIdx.x; i < SPAN * 10; i += 256) gacc[i] = 0.f;
  int n0 = blockIdx.x * 256;
  if (threadIdx.x == 0) s_bmin = batch[n0];
  __syncthreads();
  int bmin = s_bmin;
  int n = n0 + threadIdx.x;
  if (n < NN) {
    float xi[20];
    const float4* px = (const float4*)(x + (size_t)n * 20);
    { float4 t0 = px[0], t1 = px[1], t2 = px[2], t3 = px[3], t4 = px[4];
      ST4(xi, 0, t0) ST4(xi, 4, t1) ST4(xi, 8, t2) ST4(xi, 12, t3) ST4(xi, 16, t4) }
    float acc[10];
#pragma unroll
    for (int j = 0; j < 10; ++j) acc[j] = b1[j];
#pragma unroll
    for (int k = 0; k < 20; ++k) {
      float fk = xi[k];
#pragma unroll
      for (int j = 0; j < 10; ++j) acc[j] = fmaf(fk, W1[k * 10 + j], acc[j]);
    }
    int bn = batch[n];
    int d = bn - bmin;
    if (d < SPAN) {
#pragma unroll
      for (int j = 0; j < 10; ++j) {
        float m = fmaxf(acc[j], 0.f);
        if (m > 0.f) atomicAdd(&gacc[d * 10 + j], m);   // LDS
      }
    } else {
#pragma unroll
      for (int j = 0; j < 10; ++j) {
        float m = fmaxf(acc[j], 0.f);
        if (m > 0.f) unsafeAtomicAdd(&g[(size_t)bn * 10 + j], m);
      }
    }
  }
  __syncthreads();
  int lim = min(SPAN * 10, NG * 10 - bmin * 10);
  float* gp = g + (size_t)bmin * 10;
  for (int idx = threadIdx.x; idx < lim; idx += 256) {
    float v = gacc[idx];
    if (v != 0.f) unsafeAtomicAdd(&gp[idx], v);         // sparse residuals
  }
}

// ---------------- graph MLP ----------------
__global__ __launch_bounds__(256) void k_graph(
    const float* __restrict__ g,
    const float* __restrict__ W2, const float* __restrict__ b2,
    const float* __restrict__ W3, const float* __restrict__ b3,
    float* __restrict__ out) {
  int i = blockIdx.x * 256 + threadIdx.x;
  if (i >= NG) return;
  float gi[10];
  const float2* pg = (const float2*)(g + (size_t)i * 10);
#pragma unroll
  for (int k = 0; k < 5; ++k) { float2 v = pg[k]; gi[2*k] = v.x; gi[2*k+1] = v.y; }
  float o = b3[0];
#pragma unroll
  for (int j = 0; j < 10; ++j) {
    float a = b2[j];
#pragma unroll
    for (int k = 0; k < 10; ++k) a = fmaf(gi[k], W2[k * 10 + j], a);
    o = fmaf(fmaxf(a, 0.f), W3[j], o);
  }
  out[i] = o;
}

extern "C" void kernel_launch(void* const* d_in, const int* in_sizes, int n_in,
                              void* d_out, int out_size, void* d_ws, size_t ws_size,
                              hipStream_t stream) {
  const int*   ei    = (const int*)  d_in[0];
  const float* nattr = (const float*)d_in[1];
  const float* eattr = (const float*)d_in[2];
  const int*   batch = (const int*)  d_in[3];
  const float* Wm    = (const float*)d_in[4];
  const float* bm    = (const float*)d_in[5];
  const float* W1    = (const float*)d_in[6];
  const float* b1    = (const float*)d_in[7];
  const float* W2    = (const float*)d_in[8];
  const float* b2    = (const float*)d_in[9];
  const float* W3    = (const float*)d_in[10];
  const float* b3    = (const float*)d_in[11];

  float* x      = (float*)d_ws;
  float* g      = (float*)d_ws + OFF_G;
  int*   bh     = (int*)d_ws + OFF_BH;
  int*   starts = (int*)d_ws + OFF_ST;
  int*   perm   = (int*)d_ws + OFF_PM;

  constexpr int SCAN_BLKS = (NBKT + 255) / 256;   // 7

  k_hist   <<<NB, 256, 0, stream>>>(ei, bh, g);
  k_btot   <<<SCAN_BLKS, 256, 0, stream>>>(bh, starts);
  k_sscan  <<<1, 1024, 0, stream>>>(starts);
  k_bases  <<<SCAN_BLKS, 256, 0, stream>>>(bh, starts);
  k_scatter<<<NB, 256, 0, stream>>>(ei, bh, perm);
  k_edge   <<<NBKT, 256, 0, stream>>>(ei, nattr, eattr, Wm, bm, perm, starts, x);
  k_node   <<<(NN + 255) / 256, 256, 0, stream>>>(x, batch, W1, b1, g);
  k_graph  <<<(NG + 255) / 256, 256, 0, stream>>>(g, W2, b2, W3, b3, (float*)d_out);
}